// Round 5
// baseline (763.443 us; speedup 1.0000x reference)
//
#include <hip/hip_runtime.h>
#include <cmath>

#define TABLE_SZ 16384
#define NLEV 16
#define BLOCK 512
#define PPT 8          // points per thread -> 4096 points/block, grid = 256
#define HALF 8         // levels per half-pass: acc o[PPT][16], one 64B write/point

struct ResArr { float r[NLEV]; };

__global__ __launch_bounds__(BLOCK) void mrhe_kernel(
    const float* __restrict__ x,
    const float* __restrict__ tables,
    float* __restrict__ out,
    ResArr res, int B)
{
    __shared__ float2 tab[TABLE_SZ];   // 128 KiB — one level's table

    const int tid  = threadIdx.x;
    const int wid  = tid >> 6;
    const int base = blockIdx.x * (BLOCK * PPT);

    // x in [0,1): interp weight w = x - floor(x) == x exactly, so coords
    // double as trilinear weights (faithful to reference).
    float px[PPT], py[PPT], pz[PPT];
    #pragma unroll
    for (int p = 0; p < PPT; ++p) {
        int idx = base + p * BLOCK + tid;
        size_t j = (idx < B) ? (size_t)idx : 0;
        px[p] = x[3*j+0];
        py[p] = x[3*j+1];
        pz[p] = x[3*j+2];
    }

    const uint32_t P1 = 2654435761u, P2 = 805459861u;
    const uint32_t m  = TABLE_SZ - 1u;

    for (int half = 0; half < NLEV / HALF; ++half) {   // runtime loop
        float o[PPT][2*HALF];   // 128 floats — statically indexed only

        #pragma unroll
        for (int hl = 0; hl < HALF; ++hl) {
            const int l = half * HALF + hl;

            // ---- stage level-l table into LDS (async, zero staging VGPRs) ----
            __syncthreads();   // protect previous level's readers
            {
                const char* gbase = (const char*)tables + (size_t)l * (TABLE_SZ * 8);
                #pragma unroll
                for (int j = 0; j < (TABLE_SZ * 8) / (BLOCK * 16); ++j) {  // 16 rounds
                    uint32_t goff = (uint32_t)(j * (BLOCK * 16) + tid * 16);   // per-lane
                    uint32_t loff = (uint32_t)(j * (BLOCK * 16) + wid * 1024); // wave-uniform
                    __builtin_amdgcn_global_load_lds(
                        (const __attribute__((address_space(1))) uint32_t*)(gbase + goff),
                        (__attribute__((address_space(3))) uint32_t*)((char*)tab + loff),
                        16, 0, 0);
                }
            }
            __syncthreads();   // drains vmcnt before s_barrier

            const float r = res.r[l];

            #pragma unroll
            for (int p = 0; p < PPT; ++p) {
                // corner weights, product order (x*y)*z, corners v0..v7
                float ax = 1.0f - px[p], ay = 1.0f - py[p], az = 1.0f - pz[p];
                float cw0 = (ax*ay)*az;
                float cw1 = (px[p]*ay)*az;
                float cw2 = (px[p]*py[p])*az;
                float cw3 = (ax*py[p])*az;
                float cw4 = (ax*ay)*pz[p];
                float cw5 = (px[p]*ay)*pz[p];
                float cw6 = (px[p]*py[p])*pz[p];
                float cw7 = (ax*py[p])*pz[p];

                float sx = r*px[p], sy = r*py[p], sz = r*pz[p];
                // high = ceil (NOT low+1)
                uint32_t lx = (uint32_t)(int32_t)floorf(sx);
                uint32_t hx = (uint32_t)(int32_t)ceilf(sx);
                uint32_t ly = (uint32_t)(int32_t)floorf(sy);
                uint32_t hy = (uint32_t)(int32_t)ceilf(sy);
                uint32_t lz = (uint32_t)(int32_t)floorf(sz);
                uint32_t hz = (uint32_t)(int32_t)ceilf(sz);
                uint32_t yl = P1*ly, yh = P1*hy;
                uint32_t zl = P2*lz, zh = P2*hz;
                uint32_t h0 = (lx ^ yl ^ zl) & m;
                uint32_t h1 = (hx ^ yl ^ zl) & m;
                uint32_t h2 = (hx ^ yh ^ zl) & m;
                uint32_t h3 = (lx ^ yh ^ zl) & m;
                uint32_t h4 = (lx ^ yl ^ zh) & m;
                uint32_t h5 = (hx ^ yl ^ zh) & m;
                uint32_t h6 = (hx ^ yh ^ zh) & m;
                uint32_t h7 = (lx ^ yh ^ zh) & m;

                float2 f0 = tab[h0]; float2 f1 = tab[h1];
                float2 f2 = tab[h2]; float2 f3 = tab[h3];
                float2 f4 = tab[h4]; float2 f5 = tab[h5];
                float2 f6 = tab[h6]; float2 f7 = tab[h7];

                float a0 = f0.x*cw0;  float a1 = f0.y*cw0;
                a0 += f1.x*cw1;       a1 += f1.y*cw1;
                a0 += f2.x*cw2;       a1 += f2.y*cw2;
                a0 += f3.x*cw3;       a1 += f3.y*cw3;
                a0 += f4.x*cw4;       a1 += f4.y*cw4;
                a0 += f5.x*cw5;       a1 += f5.y*cw5;
                a0 += f6.x*cw6;       a1 += f6.y*cw6;
                a0 += f7.x*cw7;       a1 += f7.y*cw7;

                o[p][2*hl+0] = a0;
                o[p][2*hl+1] = a1;
            }
        }

        // ---- epilogue for this half: 64 contiguous bytes per point ----
        // (full aligned HBM sector -> no partial-write RMW/amplification)
        #pragma unroll
        for (int p = 0; p < PPT; ++p) {
            int idx = base + p * BLOCK + tid;
            if (idx < B) {
                float* po = out + (size_t)idx * (2*NLEV) + half * (2*HALF);
                #pragma unroll
                for (int j = 0; j < (2*HALF)/4; ++j) {   // 4x float4, contiguous
                    float4 v;
                    v.x = o[p][4*j+0]; v.y = o[p][4*j+1];
                    v.z = o[p][4*j+2]; v.w = o[p][4*j+3];
                    ((float4*)po)[j] = v;
                }
            }
        }
    }
}

extern "C" void kernel_launch(void* const* d_in, const int* in_sizes, int n_in,
                              void* d_out, int out_size, void* d_ws, size_t ws_size,
                              hipStream_t stream)
{
    const float* x      = (const float*)d_in[0];
    const float* tables = (const float*)d_in[1];
    float* out = (float*)d_out;
    int B = in_sizes[0] / 3;

    // Replicate the reference's float32 op chain on host libm:
    // b = exp((log(512)-log(16))/15); res_l = floor(16 * b**l)
    ResArr res;
    float bgrow = expf((logf(512.0f) - logf(16.0f)) / 15.0f);
    for (int l = 0; l < NLEV; ++l)
        res.r[l] = floorf(16.0f * powf(bgrow, (float)l));

    int per_block = BLOCK * PPT;
    int grid = (B + per_block - 1) / per_block;
    hipLaunchKernelGGL(mrhe_kernel, dim3(grid), dim3(BLOCK), 0, stream,
                       x, tables, out, res, B);
}

// Round 6
// 711.440 us; speedup vs baseline: 1.0731x; 1.0731x over previous
//
#include <hip/hip_runtime.h>
#include <cmath>

#define TABLE_SZ 16384
#define NLEV 16
#define BLOCK 512
#define PPT 4          // points per thread -> 2048 points/block, grid = 512

struct ResArr { float r[NLEV]; };

// LDS pins us to 1 block/CU (128 KiB) = 2 waves/SIMD, so up to 256 VGPR/wave
// is free. (512,1): one 8-wave block resident -> VGPR cap 256. Do NOT raise
// the 2nd arg (measured: (1024,2)->64, bare->128 => spills).
__global__ __launch_bounds__(BLOCK, 1) void mrhe_kernel(
    const float* __restrict__ x,
    const float* __restrict__ tables,
    float* __restrict__ out,
    ResArr res, int B)
{
    __shared__ float2 tab[TABLE_SZ];   // 128 KiB — one level's table

    const int tid  = threadIdx.x;
    const int wid  = tid >> 6;
    const int base = blockIdx.x * (BLOCK * PPT);

    // x in [0,1): interp weight w = x - floor(x) == x exactly, so coords
    // double as trilinear weights (faithful to reference).
    float px[PPT], py[PPT], pz[PPT];
    #pragma unroll
    for (int p = 0; p < PPT; ++p) {
        int idx = base + p * BLOCK + tid;
        size_t j = (idx < B) ? (size_t)idx : 0;
        px[p] = x[3*j+0];
        py[p] = x[3*j+1];
        pz[p] = x[3*j+2];
    }

    const uint32_t P1 = 2654435761u, P2 = 805459861u;
    const uint32_t m  = TABLE_SZ - 1u;

    float o[PPT][2*NLEV];   // 128 floats — statically indexed only (full unroll)

    #pragma unroll
    for (int l = 0; l < NLEV; ++l) {
        // ---- stage level-l table into LDS (async, zero staging VGPRs) ----
        __syncthreads();   // protect previous level's readers
        {
            const char* gbase = (const char*)tables + (size_t)l * (TABLE_SZ * 8);
            #pragma unroll
            for (int j = 0; j < (TABLE_SZ * 8) / (BLOCK * 16); ++j) {  // 16 rounds
                uint32_t goff = (uint32_t)(j * (BLOCK * 16) + tid * 16);   // per-lane
                uint32_t loff = (uint32_t)(j * (BLOCK * 16) + wid * 1024); // wave-uniform
                __builtin_amdgcn_global_load_lds(
                    (const __attribute__((address_space(1))) uint32_t*)(gbase + goff),
                    (__attribute__((address_space(3))) uint32_t*)((char*)tab + loff),
                    16, 0, 0);
            }
        }
        __syncthreads();   // drains vmcnt before s_barrier

        const float r = res.r[l];

        #pragma unroll
        for (int p = 0; p < PPT; ++p) {
            // corner weights, product order (x*y)*z, corners v0..v7
            float ax = 1.0f - px[p], ay = 1.0f - py[p], az = 1.0f - pz[p];
            float cw0 = (ax*ay)*az;
            float cw1 = (px[p]*ay)*az;
            float cw2 = (px[p]*py[p])*az;
            float cw3 = (ax*py[p])*az;
            float cw4 = (ax*ay)*pz[p];
            float cw5 = (px[p]*ay)*pz[p];
            float cw6 = (px[p]*py[p])*pz[p];
            float cw7 = (ax*py[p])*pz[p];

            float sx = r*px[p], sy = r*py[p], sz = r*pz[p];
            // high = ceil (NOT low+1)
            uint32_t lx = (uint32_t)(int32_t)floorf(sx);
            uint32_t hx = (uint32_t)(int32_t)ceilf(sx);
            uint32_t ly = (uint32_t)(int32_t)floorf(sy);
            uint32_t hy = (uint32_t)(int32_t)ceilf(sy);
            uint32_t lz = (uint32_t)(int32_t)floorf(sz);
            uint32_t hz = (uint32_t)(int32_t)ceilf(sz);
            uint32_t yl = P1*ly, yh = P1*hy;
            uint32_t zl = P2*lz, zh = P2*hz;
            uint32_t h0 = (lx ^ yl ^ zl) & m;
            uint32_t h1 = (hx ^ yl ^ zl) & m;
            uint32_t h2 = (hx ^ yh ^ zl) & m;
            uint32_t h3 = (lx ^ yh ^ zl) & m;
            uint32_t h4 = (lx ^ yl ^ zh) & m;
            uint32_t h5 = (hx ^ yl ^ zh) & m;
            uint32_t h6 = (hx ^ yh ^ zh) & m;
            uint32_t h7 = (lx ^ yh ^ zh) & m;

            float2 f0 = tab[h0]; float2 f1 = tab[h1];
            float2 f2 = tab[h2]; float2 f3 = tab[h3];
            float2 f4 = tab[h4]; float2 f5 = tab[h5];
            float2 f6 = tab[h6]; float2 f7 = tab[h7];

            float a0 = f0.x*cw0;  float a1 = f0.y*cw0;
            a0 += f1.x*cw1;       a1 += f1.y*cw1;
            a0 += f2.x*cw2;       a1 += f2.y*cw2;
            a0 += f3.x*cw3;       a1 += f3.y*cw3;
            a0 += f4.x*cw4;       a1 += f4.y*cw4;
            a0 += f5.x*cw5;       a1 += f5.y*cw5;
            a0 += f6.x*cw6;       a1 += f6.y*cw6;
            a0 += f7.x*cw7;       a1 += f7.y*cw7;

            o[p][2*l+0] = a0;
            o[p][2*l+1] = a1;
        }
    }

    // ---- epilogue: full 128 B row per point, 8x float4 back-to-back ----
    // (all 32 floats of a row hit L2 in one window -> full-sector HBM writes)
    #pragma unroll
    for (int p = 0; p < PPT; ++p) {
        int idx = base + p * BLOCK + tid;
        if (idx < B) {
            float4* po = (float4*)(out + (size_t)idx * (2*NLEV));
            #pragma unroll
            for (int j = 0; j < (2*NLEV)/4; ++j) {
                float4 v;
                v.x = o[p][4*j+0]; v.y = o[p][4*j+1];
                v.z = o[p][4*j+2]; v.w = o[p][4*j+3];
                po[j] = v;
            }
        }
    }
}

extern "C" void kernel_launch(void* const* d_in, const int* in_sizes, int n_in,
                              void* d_out, int out_size, void* d_ws, size_t ws_size,
                              hipStream_t stream)
{
    const float* x      = (const float*)d_in[0];
    const float* tables = (const float*)d_in[1];
    float* out = (float*)d_out;
    int B = in_sizes[0] / 3;

    // Replicate the reference's float32 op chain on host libm:
    // b = exp((log(512)-log(16))/15); res_l = floor(16 * b**l)
    ResArr res;
    float bgrow = expf((logf(512.0f) - logf(16.0f)) / 15.0f);
    for (int l = 0; l < NLEV; ++l)
        res.r[l] = floorf(16.0f * powf(bgrow, (float)l));

    int per_block = BLOCK * PPT;
    int grid = (B + per_block - 1) / per_block;
    hipLaunchKernelGGL(mrhe_kernel, dim3(grid), dim3(BLOCK), 0, stream,
                       x, tables, out, res, B);
}

// Round 7
// 710.686 us; speedup vs baseline: 1.0742x; 1.0011x over previous
//
#include <hip/hip_runtime.h>
#include <cmath>

#define TABLE_SZ 16384
#define NLEV 16
#define BLOCK 512
#define PPT 4          // points per thread -> 2048 points/block, grid = 512

struct ResArr { float r[NLEV]; };

// LDS (128 KiB) pins occupancy at 1 block/CU = 2 waves/SIMD, so a 256-VGPR
// budget is free. __launch_bounds__'s 2nd arg is IGNORED by the allocator
// (measured: 1024-blk->64, 512-blk->128 across args). amdgpu_waves_per_eu(2,2)
// pins the budget explicitly: 512 regs/SIMD / 2 waves = 256 VGPR cap.
__global__ __launch_bounds__(BLOCK)
__attribute__((amdgpu_waves_per_eu(2, 2)))
void mrhe_kernel(
    const float* __restrict__ x,
    const float* __restrict__ tables,
    float* __restrict__ out,
    ResArr res, int B)
{
    __shared__ float2 tab[TABLE_SZ];   // 128 KiB — one level's table

    const int tid  = threadIdx.x;
    const int wid  = tid >> 6;
    const int base = blockIdx.x * (BLOCK * PPT);

    // x in [0,1): interp weight w = x - floor(x) == x exactly, so coords
    // double as trilinear weights (faithful to reference).
    float px[PPT], py[PPT], pz[PPT];
    #pragma unroll
    for (int p = 0; p < PPT; ++p) {
        int idx = base + p * BLOCK + tid;
        size_t j = (idx < B) ? (size_t)idx : 0;
        px[p] = x[3*j+0];
        py[p] = x[3*j+1];
        pz[p] = x[3*j+2];
    }

    const uint32_t P1 = 2654435761u, P2 = 805459861u;
    const uint32_t m  = TABLE_SZ - 1u;

    float o[PPT][2*NLEV];   // 128 floats — statically indexed only (full unroll)

    #pragma unroll
    for (int l = 0; l < NLEV; ++l) {
        // ---- stage level-l table into LDS (async, zero staging VGPRs) ----
        __syncthreads();   // protect previous level's readers
        {
            const char* gbase = (const char*)tables + (size_t)l * (TABLE_SZ * 8);
            #pragma unroll
            for (int j = 0; j < (TABLE_SZ * 8) / (BLOCK * 16); ++j) {  // 16 rounds
                uint32_t goff = (uint32_t)(j * (BLOCK * 16) + tid * 16);   // per-lane
                uint32_t loff = (uint32_t)(j * (BLOCK * 16) + wid * 1024); // wave-uniform
                __builtin_amdgcn_global_load_lds(
                    (const __attribute__((address_space(1))) uint32_t*)(gbase + goff),
                    (__attribute__((address_space(3))) uint32_t*)((char*)tab + loff),
                    16, 0, 0);
            }
        }
        __syncthreads();   // drains vmcnt before s_barrier

        const float r = res.r[l];

        #pragma unroll
        for (int p = 0; p < PPT; ++p) {
            // corner weights, product order (x*y)*z, corners v0..v7
            float ax = 1.0f - px[p], ay = 1.0f - py[p], az = 1.0f - pz[p];

            float sx = r*px[p], sy = r*py[p], sz = r*pz[p];
            // high = ceil (NOT low+1)
            uint32_t lx = (uint32_t)(int32_t)floorf(sx);
            uint32_t hx = (uint32_t)(int32_t)ceilf(sx);
            uint32_t ly = (uint32_t)(int32_t)floorf(sy);
            uint32_t hy = (uint32_t)(int32_t)ceilf(sy);
            uint32_t lz = (uint32_t)(int32_t)floorf(sz);
            uint32_t hz = (uint32_t)(int32_t)ceilf(sz);
            uint32_t yl = P1*ly, yh = P1*hy;
            uint32_t zl = P2*lz, zh = P2*hz;

            float a0, a1;
            // z-low corners v0..v3 (reuse 4 gather regs, lower peak pressure)
            {
                uint32_t h0 = (lx ^ yl ^ zl) & m;
                uint32_t h1 = (hx ^ yl ^ zl) & m;
                uint32_t h2 = (hx ^ yh ^ zl) & m;
                uint32_t h3 = (lx ^ yh ^ zl) & m;
                float2 f0 = tab[h0]; float2 f1 = tab[h1];
                float2 f2 = tab[h2]; float2 f3 = tab[h3];
                float cw0 = (ax*ay)*az;
                float cw1 = (px[p]*ay)*az;
                float cw2 = (px[p]*py[p])*az;
                float cw3 = (ax*py[p])*az;
                a0  = f0.x*cw0;  a1  = f0.y*cw0;
                a0 += f1.x*cw1;  a1 += f1.y*cw1;
                a0 += f2.x*cw2;  a1 += f2.y*cw2;
                a0 += f3.x*cw3;  a1 += f3.y*cw3;
            }
            // z-high corners v4..v7
            {
                uint32_t h4 = (lx ^ yl ^ zh) & m;
                uint32_t h5 = (hx ^ yl ^ zh) & m;
                uint32_t h6 = (hx ^ yh ^ zh) & m;
                uint32_t h7 = (lx ^ yh ^ zh) & m;
                float2 f4 = tab[h4]; float2 f5 = tab[h5];
                float2 f6 = tab[h6]; float2 f7 = tab[h7];
                float cw4 = (ax*ay)*pz[p];
                float cw5 = (px[p]*ay)*pz[p];
                float cw6 = (px[p]*py[p])*pz[p];
                float cw7 = (ax*py[p])*pz[p];
                a0 += f4.x*cw4;  a1 += f4.y*cw4;
                a0 += f5.x*cw5;  a1 += f5.y*cw5;
                a0 += f6.x*cw6;  a1 += f6.y*cw6;
                a0 += f7.x*cw7;  a1 += f7.y*cw7;
            }

            o[p][2*l+0] = a0;
            o[p][2*l+1] = a1;
        }
    }

    // ---- epilogue: full 128 B row per point, 8x float4 back-to-back ----
    // (one wave fully covers each touched line -> no partial-write RMW)
    #pragma unroll
    for (int p = 0; p < PPT; ++p) {
        int idx = base + p * BLOCK + tid;
        if (idx < B) {
            float4* po = (float4*)(out + (size_t)idx * (2*NLEV));
            #pragma unroll
            for (int j = 0; j < (2*NLEV)/4; ++j) {
                float4 v;
                v.x = o[p][4*j+0]; v.y = o[p][4*j+1];
                v.z = o[p][4*j+2]; v.w = o[p][4*j+3];
                po[j] = v;
            }
        }
    }
}

extern "C" void kernel_launch(void* const* d_in, const int* in_sizes, int n_in,
                              void* d_out, int out_size, void* d_ws, size_t ws_size,
                              hipStream_t stream)
{
    const float* x      = (const float*)d_in[0];
    const float* tables = (const float*)d_in[1];
    float* out = (float*)d_out;
    int B = in_sizes[0] / 3;

    // Replicate the reference's float32 op chain on host libm:
    // b = exp((log(512)-log(16))/15); res_l = floor(16 * b**l)
    ResArr res;
    float bgrow = expf((logf(512.0f) - logf(16.0f)) / 15.0f);
    for (int l = 0; l < NLEV; ++l)
        res.r[l] = floorf(16.0f * powf(bgrow, (float)l));

    int per_block = BLOCK * PPT;
    int grid = (B + per_block - 1) / per_block;
    hipLaunchKernelGGL(mrhe_kernel, dim3(grid), dim3(BLOCK), 0, stream,
                       x, tables, out, res, B);
}

// Round 8
// 493.003 us; speedup vs baseline: 1.5486x; 1.4415x over previous
//
#include <hip/hip_runtime.h>
#include <cmath>

#define TABLE_SZ 16384
#define NLEV 16
#define BLOCK 512
#define PPT 4          // points per thread -> 2048 points/block, grid = 512
#define HALF 8         // levels per half-pass: acc o[4][16] = 64 floats

struct ResArr { float r[NLEV]; };

// Measured across 4 configs: VGPR cap for a 512-thread block is 128 and no
// source attribute (__launch_bounds__ 2nd arg, amdgpu_waves_per_eu) raises it.
// This kernel is DESIGNED for <=128 VGPRs: 64 acc floats + ~25 transients.
__global__ __launch_bounds__(BLOCK) void mrhe_kernel(
    const float* __restrict__ x,
    const float* __restrict__ tables,
    float* __restrict__ out,
    ResArr res, int B)
{
    __shared__ float2 tab[TABLE_SZ];   // 128 KiB — one level's table

    const int tid  = threadIdx.x;
    const int wid  = tid >> 6;
    const int base = blockIdx.x * (BLOCK * PPT);

    // x in [0,1): interp weight w = x - floor(x) == x exactly, so coords
    // double as trilinear weights (faithful to reference).
    float px[PPT], py[PPT], pz[PPT];
    #pragma unroll
    for (int p = 0; p < PPT; ++p) {
        int idx = base + p * BLOCK + tid;
        size_t j = (idx < B) ? (size_t)idx : 0;
        px[p] = x[3*j+0];
        py[p] = x[3*j+1];
        pz[p] = x[3*j+2];
    }

    const uint32_t P1 = 2654435761u, P2 = 805459861u;
    const uint32_t m  = TABLE_SZ - 1u;

    #pragma unroll
    for (int half = 0; half < NLEV / HALF; ++half) {
        float o[PPT][2*HALF];   // 64 floats — statically indexed only

        #pragma unroll
        for (int hl = 0; hl < HALF; ++hl) {
            const int l = half * HALF + hl;

            // ---- stage level-l table into LDS (async, zero staging VGPRs) ----
            __syncthreads();   // protect previous level's readers
            {
                const char* gbase = (const char*)tables + (size_t)l * (TABLE_SZ * 8);
                #pragma unroll
                for (int j = 0; j < (TABLE_SZ * 8) / (BLOCK * 16); ++j) {  // 16 rounds
                    uint32_t goff = (uint32_t)(j * (BLOCK * 16) + tid * 16);   // per-lane
                    uint32_t loff = (uint32_t)(j * (BLOCK * 16) + wid * 1024); // wave-uniform
                    __builtin_amdgcn_global_load_lds(
                        (const __attribute__((address_space(1))) uint32_t*)(gbase + goff),
                        (__attribute__((address_space(3))) uint32_t*)((char*)tab + loff),
                        16, 0, 0);
                }
            }
            __syncthreads();   // drains vmcnt before s_barrier

            const float r = res.r[l];

            #pragma unroll
            for (int p = 0; p < PPT; ++p) {
                // corner weights, product order (x*y)*z, corners v0..v7
                float ax = 1.0f - px[p], ay = 1.0f - py[p], az = 1.0f - pz[p];

                float sx = r*px[p], sy = r*py[p], sz = r*pz[p];
                // high = ceil (NOT low+1)
                uint32_t lx = (uint32_t)(int32_t)floorf(sx);
                uint32_t hx = (uint32_t)(int32_t)ceilf(sx);
                uint32_t ly = (uint32_t)(int32_t)floorf(sy);
                uint32_t hy = (uint32_t)(int32_t)ceilf(sy);
                uint32_t lz = (uint32_t)(int32_t)floorf(sz);
                uint32_t hz = (uint32_t)(int32_t)ceilf(sz);
                uint32_t yl = P1*ly, yh = P1*hy;
                uint32_t zl = P2*lz, zh = P2*hz;

                float a0, a1;
                // z-low corners v0..v3 (reuse gather regs, lower peak pressure)
                {
                    uint32_t h0 = (lx ^ yl ^ zl) & m;
                    uint32_t h1 = (hx ^ yl ^ zl) & m;
                    uint32_t h2 = (hx ^ yh ^ zl) & m;
                    uint32_t h3 = (lx ^ yh ^ zl) & m;
                    float2 f0 = tab[h0]; float2 f1 = tab[h1];
                    float2 f2 = tab[h2]; float2 f3 = tab[h3];
                    float cw0 = (ax*ay)*az;
                    float cw1 = (px[p]*ay)*az;
                    float cw2 = (px[p]*py[p])*az;
                    float cw3 = (ax*py[p])*az;
                    a0  = f0.x*cw0;  a1  = f0.y*cw0;
                    a0 += f1.x*cw1;  a1 += f1.y*cw1;
                    a0 += f2.x*cw2;  a1 += f2.y*cw2;
                    a0 += f3.x*cw3;  a1 += f3.y*cw3;
                }
                // z-high corners v4..v7
                {
                    uint32_t h4 = (lx ^ yl ^ zh) & m;
                    uint32_t h5 = (hx ^ yl ^ zh) & m;
                    uint32_t h6 = (hx ^ yh ^ zh) & m;
                    uint32_t h7 = (lx ^ yh ^ zh) & m;
                    float2 f4 = tab[h4]; float2 f5 = tab[h5];
                    float2 f6 = tab[h6]; float2 f7 = tab[h7];
                    float cw4 = (ax*ay)*pz[p];
                    float cw5 = (px[p]*ay)*pz[p];
                    float cw6 = (px[p]*py[p])*pz[p];
                    float cw7 = (ax*py[p])*pz[p];
                    a0 += f4.x*cw4;  a1 += f4.y*cw4;
                    a0 += f5.x*cw5;  a1 += f5.y*cw5;
                    a0 += f6.x*cw6;  a1 += f6.y*cw6;
                    a0 += f7.x*cw7;  a1 += f7.y*cw7;
                }

                o[p][2*hl+0] = a0;
                o[p][2*hl+1] = a1;
            }
        }

        // ---- epilogue: 64 contiguous 64B-aligned bytes per point ----
        // (full HBM sectors -> no RMW, no write amplification; measured
        //  sector size 64B from round-4 counters)
        #pragma unroll
        for (int p = 0; p < PPT; ++p) {
            int idx = base + p * BLOCK + tid;
            if (idx < B) {
                float* po = out + (size_t)idx * (2*NLEV) + half * (2*HALF);
                #pragma unroll
                for (int j = 0; j < (2*HALF)/4; ++j) {   // 4x float4
                    float4 v;
                    v.x = o[p][4*j+0]; v.y = o[p][4*j+1];
                    v.z = o[p][4*j+2]; v.w = o[p][4*j+3];
                    ((float4*)po)[j] = v;
                }
            }
        }
    }
}

extern "C" void kernel_launch(void* const* d_in, const int* in_sizes, int n_in,
                              void* d_out, int out_size, void* d_ws, size_t ws_size,
                              hipStream_t stream)
{
    const float* x      = (const float*)d_in[0];
    const float* tables = (const float*)d_in[1];
    float* out = (float*)d_out;
    int B = in_sizes[0] / 3;

    // Replicate the reference's float32 op chain on host libm:
    // b = exp((log(512)-log(16))/15); res_l = floor(16 * b**l)
    ResArr res;
    float bgrow = expf((logf(512.0f) - logf(16.0f)) / 15.0f);
    for (int l = 0; l < NLEV; ++l)
        res.r[l] = floorf(16.0f * powf(bgrow, (float)l));

    int per_block = BLOCK * PPT;
    int grid = (B + per_block - 1) / per_block;
    hipLaunchKernelGGL(mrhe_kernel, dim3(grid), dim3(BLOCK), 0, stream,
                       x, tables, out, res, B);
}

// Round 9
// 240.923 us; speedup vs baseline: 3.1688x; 2.0463x over previous
//
#include <hip/hip_runtime.h>
#include <cmath>

#define TABLE_SZ 16384
#define NLEV 16
#define BLOCK 256

struct ResArr { float r[NLEV]; };

// ---- shared per-level helpers ----------------------------------------------

__device__ __forceinline__ void stage_level(const float* __restrict__ tables,
                                            int l, float2* tab, int tid, int wid)
{
    const char* gbase = (const char*)tables + (size_t)l * (TABLE_SZ * 8);
    #pragma unroll
    for (int j = 0; j < (TABLE_SZ * 8) / (BLOCK * 16); ++j) {   // 32 rounds
        uint32_t goff = (uint32_t)(j * (BLOCK * 16) + tid * 16);   // per-lane
        uint32_t loff = (uint32_t)(j * (BLOCK * 16) + wid * 1024); // wave-uniform
        __builtin_amdgcn_global_load_lds(
            (const __attribute__((address_space(1))) uint32_t*)(gbase + goff),
            (__attribute__((address_space(3))) uint32_t*)((char*)tab + loff),
            16, 0, 0);
    }
}

// One point, one level: 8 corner gathers from LDS + trilinear reduce.
// x in [0,1): interp weight w = x - floor(x) == x exactly, so coords double
// as trilinear weights (faithful to reference). Product order (x*y)*z,
// corners v0..v7, k-ascending accumulation; high = ceil (NOT low+1).
__device__ __forceinline__ float2 level_accum(const float2* tab, float r,
                                              float px, float py, float pz)
{
    const uint32_t P1 = 2654435761u, P2 = 805459861u;
    const uint32_t m  = TABLE_SZ - 1u;

    float ax = 1.0f - px, ay = 1.0f - py, az = 1.0f - pz;

    float sx = r*px, sy = r*py, sz = r*pz;
    uint32_t lx = (uint32_t)(int32_t)floorf(sx);
    uint32_t hx = (uint32_t)(int32_t)ceilf(sx);
    uint32_t ly = (uint32_t)(int32_t)floorf(sy);
    uint32_t hy = (uint32_t)(int32_t)ceilf(sy);
    uint32_t lz = (uint32_t)(int32_t)floorf(sz);
    uint32_t hz = (uint32_t)(int32_t)ceilf(sz);
    uint32_t yl = P1*ly, yh = P1*hy;
    uint32_t zl = P2*lz, zh = P2*hz;

    float a0, a1;
    {   // z-low corners v0..v3 (reuse gather regs -> lower peak pressure)
        uint32_t h0 = (lx ^ yl ^ zl) & m;
        uint32_t h1 = (hx ^ yl ^ zl) & m;
        uint32_t h2 = (hx ^ yh ^ zl) & m;
        uint32_t h3 = (lx ^ yh ^ zl) & m;
        float2 f0 = tab[h0]; float2 f1 = tab[h1];
        float2 f2 = tab[h2]; float2 f3 = tab[h3];
        float cw0 = (ax*ay)*az;
        float cw1 = (px*ay)*az;
        float cw2 = (px*py)*az;
        float cw3 = (ax*py)*az;
        a0  = f0.x*cw0;  a1  = f0.y*cw0;
        a0 += f1.x*cw1;  a1 += f1.y*cw1;
        a0 += f2.x*cw2;  a1 += f2.y*cw2;
        a0 += f3.x*cw3;  a1 += f3.y*cw3;
    }
    {   // z-high corners v4..v7
        uint32_t h4 = (lx ^ yl ^ zh) & m;
        uint32_t h5 = (hx ^ yl ^ zh) & m;
        uint32_t h6 = (hx ^ yh ^ zh) & m;
        uint32_t h7 = (lx ^ yh ^ zh) & m;
        float2 f4 = tab[h4]; float2 f5 = tab[h5];
        float2 f6 = tab[h6]; float2 f7 = tab[h7];
        float cw4 = (ax*ay)*pz;
        float cw5 = (px*ay)*pz;
        float cw6 = (px*py)*pz;
        float cw7 = (ax*py)*pz;
        a0 += f4.x*cw4;  a1 += f4.y*cw4;
        a0 += f5.x*cw5;  a1 += f5.y*cw5;
        a0 += f6.x*cw6;  a1 += f6.y*cw6;
        a0 += f7.x*cw7;  a1 += f7.y*cw7;
    }
    return make_float2(a0, a1);
}

// ---- Variant A: 256-thr block (VGPR cap should be 256), PPT=4, all 16
// levels accumulated in regs (128 floats), single full-row epilogue. --------
#define PPTA 4
__global__ __launch_bounds__(BLOCK) void mrhe_full(
    const float* __restrict__ x,
    const float* __restrict__ tables,
    float* __restrict__ out,
    ResArr res, int B)
{
    __shared__ float2 tab[TABLE_SZ];   // 128 KiB

    const int tid  = threadIdx.x;
    const int wid  = tid >> 6;
    const int base = blockIdx.x * (BLOCK * PPTA);

    float px[PPTA], py[PPTA], pz[PPTA];
    #pragma unroll
    for (int p = 0; p < PPTA; ++p) {
        int idx = base + p * BLOCK + tid;
        size_t j = (idx < B) ? (size_t)idx : 0;
        px[p] = x[3*j+0]; py[p] = x[3*j+1]; pz[p] = x[3*j+2];
    }

    float o[PPTA][2*NLEV];   // 128 floats — statically indexed only

    #pragma unroll
    for (int l = 0; l < NLEV; ++l) {
        __syncthreads();                       // protect previous level's readers
        stage_level(tables, l, tab, tid, wid); // async, zero staging VGPRs
        __syncthreads();                       // drains vmcnt before s_barrier

        const float r = res.r[l];
        #pragma unroll
        for (int p = 0; p < PPTA; ++p) {
            float2 a = level_accum(tab, r, px[p], py[p], pz[p]);
            o[p][2*l+0] = a.x;
            o[p][2*l+1] = a.y;
        }
    }

    // full 128 B row per point, 8x float4 back-to-back (full sectors, no RMW)
    #pragma unroll
    for (int p = 0; p < PPTA; ++p) {
        int idx = base + p * BLOCK + tid;
        if (idx < B) {
            float4* po = (float4*)(out + (size_t)idx * (2*NLEV));
            #pragma unroll
            for (int j = 0; j < (2*NLEV)/4; ++j) {
                float4 v;
                v.x = o[p][4*j+0]; v.y = o[p][4*j+1];
                v.z = o[p][4*j+2]; v.w = o[p][4*j+3];
                po[j] = v;
            }
        }
    }
}

// ---- Variant B: low-pressure fallback (fits a 128 cap): PPT=2, two
// half-passes of 8 levels, 64 B write windows (full sectors). ---------------
#define PPTB 2
#define HALFB 8
__global__ __launch_bounds__(BLOCK) void mrhe_half(
    const float* __restrict__ x,
    const float* __restrict__ tables,
    float* __restrict__ out,
    ResArr res, int B)
{
    __shared__ float2 tab[TABLE_SZ];

    const int tid  = threadIdx.x;
    const int wid  = tid >> 6;
    const int base = blockIdx.x * (BLOCK * PPTB);

    float px[PPTB], py[PPTB], pz[PPTB];
    #pragma unroll
    for (int p = 0; p < PPTB; ++p) {
        int idx = base + p * BLOCK + tid;
        size_t j = (idx < B) ? (size_t)idx : 0;
        px[p] = x[3*j+0]; py[p] = x[3*j+1]; pz[p] = x[3*j+2];
    }

    #pragma unroll
    for (int half = 0; half < NLEV / HALFB; ++half) {
        float o[PPTB][2*HALFB];   // 32 floats

        #pragma unroll
        for (int hl = 0; hl < HALFB; ++hl) {
            const int l = half * HALFB + hl;
            __syncthreads();
            stage_level(tables, l, tab, tid, wid);
            __syncthreads();

            const float r = res.r[l];
            #pragma unroll
            for (int p = 0; p < PPTB; ++p) {
                float2 a = level_accum(tab, r, px[p], py[p], pz[p]);
                o[p][2*hl+0] = a.x;
                o[p][2*hl+1] = a.y;
            }
        }

        #pragma unroll
        for (int p = 0; p < PPTB; ++p) {
            int idx = base + p * BLOCK + tid;
            if (idx < B) {
                float* po = out + (size_t)idx * (2*NLEV) + half * (2*HALFB);
                #pragma unroll
                for (int j = 0; j < (2*HALFB)/4; ++j) {
                    float4 v;
                    v.x = o[p][4*j+0]; v.y = o[p][4*j+1];
                    v.z = o[p][4*j+2]; v.w = o[p][4*j+3];
                    ((float4*)po)[j] = v;
                }
            }
        }
    }
}

extern "C" void kernel_launch(void* const* d_in, const int* in_sizes, int n_in,
                              void* d_out, int out_size, void* d_ws, size_t ws_size,
                              hipStream_t stream)
{
    const float* x      = (const float*)d_in[0];
    const float* tables = (const float*)d_in[1];
    float* out = (float*)d_out;
    int B = in_sizes[0] / 3;

    // Replicate the reference's float32 op chain on host libm:
    // b = exp((log(512)-log(16))/15); res_l = floor(16 * b**l)
    ResArr res;
    float bgrow = expf((logf(512.0f) - logf(16.0f)) / 15.0f);
    for (int l = 0; l < NLEV; ++l)
        res.r[l] = floorf(16.0f * powf(bgrow, (float)l));

    // Pick variant A unless it spilled to scratch (host-side attribute query:
    // capture-safe, stateless, deterministic — same binary -> same choice).
    hipFuncAttributes attr{};
    hipError_t e = hipFuncGetAttributes(&attr, (const void*)mrhe_full);
    bool useA = (e == hipSuccess) && (attr.localSizeBytes == 0);

    if (useA) {
        int per_block = BLOCK * PPTA;
        int grid = (B + per_block - 1) / per_block;
        hipLaunchKernelGGL(mrhe_full, dim3(grid), dim3(BLOCK), 0, stream,
                           x, tables, out, res, B);
    } else {
        int per_block = BLOCK * PPTB;
        int grid = (B + per_block - 1) / per_block;
        hipLaunchKernelGGL(mrhe_half, dim3(grid), dim3(BLOCK), 0, stream,
                           x, tables, out, res, B);
    }
}

// Round 10
// 133.820 us; speedup vs baseline: 5.7050x; 1.8004x over previous
//
#include <hip/hip_runtime.h>
#include <cmath>

#define TABLE_SZ 16384
#define NLEV 16
#define BLOCK 256
#define PPT 4          // points per thread -> 1024 points/block, grid = 1024
#define HALF 8         // levels per half-pass: acc o[4][16] = 64 floats

struct ResArr { float r[NLEV]; };

// ---------------- prologue: tables f32 -> packed bf16x2 (RNE) ---------------
__global__ __launch_bounds__(256) void cvt_tables(
    const float* __restrict__ src, uint32_t* __restrict__ dst, int n_entries)
{
    int i = blockIdx.x * blockDim.x + threadIdx.x;   // one entry = float2 -> u32
    int e = i * 4;
    if (e + 3 < n_entries) {
        const float4* s4 = (const float4*)(src) + i * 2;
        float4 a = s4[0], b = s4[1];
        uint32_t o[4];
        float v[8] = {a.x,a.y,a.z,a.w,b.x,b.y,b.z,b.w};
        #pragma unroll
        for (int k = 0; k < 4; ++k) {
            uint32_t lo = __float_as_uint(v[2*k+0]);
            uint32_t hi = __float_as_uint(v[2*k+1]);
            lo = (lo + 0x7FFFu + ((lo >> 16) & 1u)) >> 16;     // RNE to bf16
            hi = (hi + 0x7FFFu + ((hi >> 16) & 1u)) & 0xFFFF0000u;
            o[k] = lo | hi;                                     // lo=feat0, hi=feat1
        }
        *(uint4*)(dst + e) = make_uint4(o[0], o[1], o[2], o[3]);
    }
}

// ---------------- shared helpers -------------------------------------------
template <typename T>
__device__ __forceinline__ void stage_level(const T* __restrict__ gsrc,
                                            size_t level_bytes, int l,
                                            void* lds, int tid, int wid)
{
    const char* gbase = (const char*)gsrc + (size_t)l * level_bytes;
    const int rounds = (int)(level_bytes / (BLOCK * 16));
    #pragma unroll
    for (int j = 0; j < 16; ++j) {            // bf16: 16 rounds; f32 uses 32
        if (j >= rounds) break;
        uint32_t goff = (uint32_t)(j * (BLOCK * 16) + tid * 16);   // per-lane
        uint32_t loff = (uint32_t)(j * (BLOCK * 16) + wid * 1024); // wave-uniform
        __builtin_amdgcn_global_load_lds(
            (const __attribute__((address_space(1))) uint32_t*)(gbase + goff),
            (__attribute__((address_space(3))) uint32_t*)((char*)lds + loff),
            16, 0, 0);
    }
}

// x in [0,1): interp weight w = x - floor(x) == x exactly, so coords double
// as trilinear weights (faithful). Product order (x*y)*z, corners v0..v7,
// k-ascending accumulation; high = ceil (NOT low+1). bf16x2-packed table.
__device__ __forceinline__ float2 level_accum_bf(const uint32_t* tab, float r,
                                                 float px, float py, float pz)
{
    const uint32_t P1 = 2654435761u, P2 = 805459861u;
    const uint32_t m  = TABLE_SZ - 1u;

    float ax = 1.0f - px, ay = 1.0f - py, az = 1.0f - pz;
    float sx = r*px, sy = r*py, sz = r*pz;
    uint32_t lx = (uint32_t)(int32_t)floorf(sx);
    uint32_t hx = (uint32_t)(int32_t)ceilf(sx);
    uint32_t ly = (uint32_t)(int32_t)floorf(sy);
    uint32_t hy = (uint32_t)(int32_t)ceilf(sy);
    uint32_t lz = (uint32_t)(int32_t)floorf(sz);
    uint32_t hz = (uint32_t)(int32_t)ceilf(sz);
    uint32_t yl = P1*ly, yh = P1*hy;
    uint32_t zl = P2*lz, zh = P2*hz;

    float a0, a1;
    {   // z-low corners v0..v3
        uint32_t v0 = tab[(lx ^ yl ^ zl) & m];
        uint32_t v1 = tab[(hx ^ yl ^ zl) & m];
        uint32_t v2 = tab[(hx ^ yh ^ zl) & m];
        uint32_t v3 = tab[(lx ^ yh ^ zl) & m];
        float cw0 = (ax*ay)*az;
        float cw1 = (px*ay)*az;
        float cw2 = (px*py)*az;
        float cw3 = (ax*py)*az;
        a0  = __uint_as_float(v0 << 16)        * cw0;
        a1  = __uint_as_float(v0 & 0xFFFF0000u) * cw0;
        a0 += __uint_as_float(v1 << 16)        * cw1;
        a1 += __uint_as_float(v1 & 0xFFFF0000u) * cw1;
        a0 += __uint_as_float(v2 << 16)        * cw2;
        a1 += __uint_as_float(v2 & 0xFFFF0000u) * cw2;
        a0 += __uint_as_float(v3 << 16)        * cw3;
        a1 += __uint_as_float(v3 & 0xFFFF0000u) * cw3;
    }
    {   // z-high corners v4..v7
        uint32_t v4 = tab[(lx ^ yl ^ zh) & m];
        uint32_t v5 = tab[(hx ^ yl ^ zh) & m];
        uint32_t v6 = tab[(hx ^ yh ^ zh) & m];
        uint32_t v7 = tab[(lx ^ yh ^ zh) & m];
        float cw4 = (ax*ay)*pz;
        float cw5 = (px*ay)*pz;
        float cw6 = (px*py)*pz;
        float cw7 = (ax*py)*pz;
        a0 += __uint_as_float(v4 << 16)        * cw4;
        a1 += __uint_as_float(v4 & 0xFFFF0000u) * cw4;
        a0 += __uint_as_float(v5 << 16)        * cw5;
        a1 += __uint_as_float(v5 & 0xFFFF0000u) * cw5;
        a0 += __uint_as_float(v6 << 16)        * cw6;
        a1 += __uint_as_float(v6 & 0xFFFF0000u) * cw6;
        a0 += __uint_as_float(v7 << 16)        * cw7;
        a1 += __uint_as_float(v7 & 0xFFFF0000u) * cw7;
    }
    return make_float2(a0, a1);
}

__device__ __forceinline__ float2 level_accum_f32(const float2* tab, float r,
                                                  float px, float py, float pz)
{
    const uint32_t P1 = 2654435761u, P2 = 805459861u;
    const uint32_t m  = TABLE_SZ - 1u;
    float ax = 1.0f - px, ay = 1.0f - py, az = 1.0f - pz;
    float sx = r*px, sy = r*py, sz = r*pz;
    uint32_t lx = (uint32_t)(int32_t)floorf(sx);
    uint32_t hx = (uint32_t)(int32_t)ceilf(sx);
    uint32_t ly = (uint32_t)(int32_t)floorf(sy);
    uint32_t hy = (uint32_t)(int32_t)ceilf(sy);
    uint32_t lz = (uint32_t)(int32_t)floorf(sz);
    uint32_t hz = (uint32_t)(int32_t)ceilf(sz);
    uint32_t yl = P1*ly, yh = P1*hy;
    uint32_t zl = P2*lz, zh = P2*hz;
    float a0, a1;
    {
        float2 f0 = tab[(lx ^ yl ^ zl) & m];
        float2 f1 = tab[(hx ^ yl ^ zl) & m];
        float2 f2 = tab[(hx ^ yh ^ zl) & m];
        float2 f3 = tab[(lx ^ yh ^ zl) & m];
        float cw0 = (ax*ay)*az, cw1 = (px*ay)*az, cw2 = (px*py)*az, cw3 = (ax*py)*az;
        a0  = f0.x*cw0;  a1  = f0.y*cw0;
        a0 += f1.x*cw1;  a1 += f1.y*cw1;
        a0 += f2.x*cw2;  a1 += f2.y*cw2;
        a0 += f3.x*cw3;  a1 += f3.y*cw3;
    }
    {
        float2 f4 = tab[(lx ^ yl ^ zh) & m];
        float2 f5 = tab[(hx ^ yl ^ zh) & m];
        float2 f6 = tab[(hx ^ yh ^ zh) & m];
        float2 f7 = tab[(lx ^ yh ^ zh) & m];
        float cw4 = (ax*ay)*pz, cw5 = (px*ay)*pz, cw6 = (px*py)*pz, cw7 = (ax*py)*pz;
        a0 += f4.x*cw4;  a1 += f4.y*cw4;
        a0 += f5.x*cw5;  a1 += f5.y*cw5;
        a0 += f6.x*cw6;  a1 += f6.y*cw6;
        a0 += f7.x*cw7;  a1 += f7.y*cw7;
    }
    return make_float2(a0, a1);
}

// ---------------- main kernel: bf16 LDS (64 KiB -> 2 blocks/CU) -------------
__global__ __launch_bounds__(BLOCK) void mrhe_bf(
    const float* __restrict__ x,
    const uint32_t* __restrict__ tb,   // packed bf16x2 tables in d_ws
    float* __restrict__ out,
    ResArr res, int B)
{
    __shared__ uint32_t tab[TABLE_SZ];   // 64 KiB

    const int tid  = threadIdx.x;
    const int wid  = tid >> 6;
    const int base = blockIdx.x * (BLOCK * PPT);

    float px[PPT], py[PPT], pz[PPT];
    #pragma unroll
    for (int p = 0; p < PPT; ++p) {
        int idx = base + p * BLOCK + tid;
        size_t j = (idx < B) ? (size_t)idx : 0;
        px[p] = x[3*j+0]; py[p] = x[3*j+1]; pz[p] = x[3*j+2];
    }

    #pragma unroll
    for (int half = 0; half < NLEV / HALF; ++half) {
        float o[PPT][2*HALF];   // 64 floats — statically indexed only

        #pragma unroll
        for (int hl = 0; hl < HALF; ++hl) {
            const int l = half * HALF + hl;
            __syncthreads();
            stage_level(tb, (size_t)TABLE_SZ * 4, l, tab, tid, wid);
            __syncthreads();

            const float r = res.r[l];
            #pragma unroll
            for (int p = 0; p < PPT; ++p) {
                float2 a = level_accum_bf(tab, r, px[p], py[p], pz[p]);
                o[p][2*hl+0] = a.x;
                o[p][2*hl+1] = a.y;
            }
        }

        // 64 contiguous 64B-aligned bytes per point (full sectors, no RMW)
        #pragma unroll
        for (int p = 0; p < PPT; ++p) {
            int idx = base + p * BLOCK + tid;
            if (idx < B) {
                float* po = out + (size_t)idx * (2*NLEV) + half * (2*HALF);
                #pragma unroll
                for (int j = 0; j < (2*HALF)/4; ++j) {
                    float4 v;
                    v.x = o[p][4*j+0]; v.y = o[p][4*j+1];
                    v.z = o[p][4*j+2]; v.w = o[p][4*j+3];
                    ((float4*)po)[j] = v;
                }
            }
        }
    }
}

// ---------------- fallback: round-9 f32 path (if ws too small) --------------
#define PPTF 2
__global__ __launch_bounds__(BLOCK) void mrhe_f32(
    const float* __restrict__ x,
    const float* __restrict__ tables,
    float* __restrict__ out,
    ResArr res, int B)
{
    __shared__ float2 tab[TABLE_SZ];   // 128 KiB

    const int tid  = threadIdx.x;
    const int wid  = tid >> 6;
    const int base = blockIdx.x * (BLOCK * PPTF);

    float px[PPTF], py[PPTF], pz[PPTF];
    #pragma unroll
    for (int p = 0; p < PPTF; ++p) {
        int idx = base + p * BLOCK + tid;
        size_t j = (idx < B) ? (size_t)idx : 0;
        px[p] = x[3*j+0]; py[p] = x[3*j+1]; pz[p] = x[3*j+2];
    }

    #pragma unroll
    for (int half = 0; half < NLEV / HALF; ++half) {
        float o[PPTF][2*HALF];
        #pragma unroll
        for (int hl = 0; hl < HALF; ++hl) {
            const int l = half * HALF + hl;
            __syncthreads();
            {   // 32 rounds of 16B
                const char* gbase = (const char*)tables + (size_t)l * (TABLE_SZ * 8);
                #pragma unroll
                for (int j = 0; j < (TABLE_SZ * 8) / (BLOCK * 16); ++j) {
                    uint32_t goff = (uint32_t)(j * (BLOCK * 16) + tid * 16);
                    uint32_t loff = (uint32_t)(j * (BLOCK * 16) + wid * 1024);
                    __builtin_amdgcn_global_load_lds(
                        (const __attribute__((address_space(1))) uint32_t*)(gbase + goff),
                        (__attribute__((address_space(3))) uint32_t*)((char*)tab + loff),
                        16, 0, 0);
                }
            }
            __syncthreads();
            const float r = res.r[l];
            #pragma unroll
            for (int p = 0; p < PPTF; ++p) {
                float2 a = level_accum_f32(tab, r, px[p], py[p], pz[p]);
                o[p][2*hl+0] = a.x;
                o[p][2*hl+1] = a.y;
            }
        }
        #pragma unroll
        for (int p = 0; p < PPTF; ++p) {
            int idx = base + p * BLOCK + tid;
            if (idx < B) {
                float* po = out + (size_t)idx * (2*NLEV) + half * (2*HALF);
                #pragma unroll
                for (int j = 0; j < (2*HALF)/4; ++j) {
                    float4 v;
                    v.x = o[p][4*j+0]; v.y = o[p][4*j+1];
                    v.z = o[p][4*j+2]; v.w = o[p][4*j+3];
                    ((float4*)po)[j] = v;
                }
            }
        }
    }
}

extern "C" void kernel_launch(void* const* d_in, const int* in_sizes, int n_in,
                              void* d_out, int out_size, void* d_ws, size_t ws_size,
                              hipStream_t stream)
{
    const float* x      = (const float*)d_in[0];
    const float* tables = (const float*)d_in[1];
    float* out = (float*)d_out;
    int B = in_sizes[0] / 3;

    // b = exp((log(512)-log(16))/15); res_l = floor(16 * b**l)  (host libm)
    ResArr res;
    float bgrow = expf((logf(512.0f) - logf(16.0f)) / 15.0f);
    for (int l = 0; l < NLEV; ++l)
        res.r[l] = floorf(16.0f * powf(bgrow, (float)l));

    const int n_entries = NLEV * TABLE_SZ;              // 262144
    const size_t need = (size_t)n_entries * 4;          // 1 MiB packed bf16x2

    if (ws_size >= need && d_ws) {
        uint32_t* tb = (uint32_t*)d_ws;
        // prologue: convert tables once per launch (deterministic)
        hipLaunchKernelGGL(cvt_tables, dim3(n_entries/4/256), dim3(256), 0, stream,
                           tables, tb, n_entries);
        int per_block = BLOCK * PPT;
        int grid = (B + per_block - 1) / per_block;
        hipLaunchKernelGGL(mrhe_bf, dim3(grid), dim3(BLOCK), 0, stream,
                           x, tb, out, res, B);
    } else {
        int per_block = BLOCK * PPTF;
        int grid = (B + per_block - 1) / per_block;
        hipLaunchKernelGGL(mrhe_f32, dim3(grid), dim3(BLOCK), 0, stream,
                           x, tables, out, res, B);
    }
}

// Round 11
// 116.089 us; speedup vs baseline: 6.5764x; 1.1527x over previous
//
#include <hip/hip_runtime.h>
#include <cmath>

#define TABLE_SZ 16384
#define NLEV 16
#define BLOCK 256
#define PPT 4          // points per thread -> 1024 points/block, grid = 1024
#define HALF 8         // levels per half-pass window (64 B full-sector writes)

struct ResArr { float r[NLEV]; };

// ---------------- prologue: tables f32 -> packed bf16x2 (RNE) ---------------
__global__ __launch_bounds__(256) void cvt_tables(
    const float* __restrict__ src, uint32_t* __restrict__ dst, int n_entries)
{
    int i = blockIdx.x * blockDim.x + threadIdx.x;   // 4 entries per thread
    int e = i * 4;
    if (e + 3 < n_entries) {
        const float4* s4 = (const float4*)(src) + i * 2;
        float4 a = s4[0], b = s4[1];
        uint32_t o[4];
        float v[8] = {a.x,a.y,a.z,a.w,b.x,b.y,b.z,b.w};
        #pragma unroll
        for (int k = 0; k < 4; ++k) {
            uint32_t lo = __float_as_uint(v[2*k+0]);
            uint32_t hi = __float_as_uint(v[2*k+1]);
            lo = (lo + 0x7FFFu + ((lo >> 16) & 1u)) >> 16;     // RNE to bf16
            hi = (hi + 0x7FFFu + ((hi >> 16) & 1u)) & 0xFFFF0000u;
            o[k] = lo | hi;                                     // lo=feat0, hi=feat1
        }
        *(uint4*)(dst + e) = make_uint4(o[0], o[1], o[2], o[3]);
    }
}

// ---------------- helpers ----------------------------------------------------
// Issue 16 global_load_lds (16 B each) staging one bf16 level (64 KiB) into buf.
// Exactly 16 vmcnt entries per wave. LDS dest is wave-uniform base + lane*16.
__device__ __forceinline__ void stage_bf(const uint32_t* __restrict__ tb, int l,
                                         uint32_t* buf, int tid, int wid)
{
    const char* gbase = (const char*)tb + (size_t)l * (TABLE_SZ * 4);
    #pragma unroll
    for (int j = 0; j < (TABLE_SZ * 4) / (BLOCK * 16); ++j) {   // 16 rounds
        uint32_t goff = (uint32_t)(j * (BLOCK * 16) + tid * 16);   // per-lane
        uint32_t loff = (uint32_t)(j * (BLOCK * 16) + wid * 1024); // wave-uniform
        __builtin_amdgcn_global_load_lds(
            (const __attribute__((address_space(1))) uint32_t*)(gbase + goff),
            (__attribute__((address_space(3))) uint32_t*)((char*)buf + loff),
            16, 0, 0);
    }
}

// x in [0,1): interp weight w = x - floor(x) == x exactly, so coords double
// as trilinear weights (faithful). Product order (x*y)*z, corners v0..v7,
// k-ascending accumulation; high = ceil (NOT low+1). bf16x2-packed table.
__device__ __forceinline__ float2 level_accum_bf(const uint32_t* tab, float r,
                                                 float px, float py, float pz)
{
    const uint32_t P1 = 2654435761u, P2 = 805459861u;
    const uint32_t m  = TABLE_SZ - 1u;

    float ax = 1.0f - px, ay = 1.0f - py, az = 1.0f - pz;
    float sx = r*px, sy = r*py, sz = r*pz;
    uint32_t lx = (uint32_t)(int32_t)floorf(sx);
    uint32_t hx = (uint32_t)(int32_t)ceilf(sx);
    uint32_t ly = (uint32_t)(int32_t)floorf(sy);
    uint32_t hy = (uint32_t)(int32_t)ceilf(sy);
    uint32_t lz = (uint32_t)(int32_t)floorf(sz);
    uint32_t hz = (uint32_t)(int32_t)ceilf(sz);
    uint32_t yl = P1*ly, yh = P1*hy;
    uint32_t zl = P2*lz, zh = P2*hz;

    float a0, a1;
    {   // z-low corners v0..v3
        uint32_t v0 = tab[(lx ^ yl ^ zl) & m];
        uint32_t v1 = tab[(hx ^ yl ^ zl) & m];
        uint32_t v2 = tab[(hx ^ yh ^ zl) & m];
        uint32_t v3 = tab[(lx ^ yh ^ zl) & m];
        float cw0 = (ax*ay)*az;
        float cw1 = (px*ay)*az;
        float cw2 = (px*py)*az;
        float cw3 = (ax*py)*az;
        a0  = __uint_as_float(v0 << 16)         * cw0;
        a1  = __uint_as_float(v0 & 0xFFFF0000u) * cw0;
        a0 += __uint_as_float(v1 << 16)         * cw1;
        a1 += __uint_as_float(v1 & 0xFFFF0000u) * cw1;
        a0 += __uint_as_float(v2 << 16)         * cw2;
        a1 += __uint_as_float(v2 & 0xFFFF0000u) * cw2;
        a0 += __uint_as_float(v3 << 16)         * cw3;
        a1 += __uint_as_float(v3 & 0xFFFF0000u) * cw3;
    }
    {   // z-high corners v4..v7
        uint32_t v4 = tab[(lx ^ yl ^ zh) & m];
        uint32_t v5 = tab[(hx ^ yl ^ zh) & m];
        uint32_t v6 = tab[(hx ^ yh ^ zh) & m];
        uint32_t v7 = tab[(lx ^ yh ^ zh) & m];
        float cw4 = (ax*ay)*pz;
        float cw5 = (px*ay)*pz;
        float cw6 = (px*py)*pz;
        float cw7 = (ax*py)*pz;
        a0 += __uint_as_float(v4 << 16)         * cw4;
        a1 += __uint_as_float(v4 & 0xFFFF0000u) * cw4;
        a0 += __uint_as_float(v5 << 16)         * cw5;
        a1 += __uint_as_float(v5 & 0xFFFF0000u) * cw5;
        a0 += __uint_as_float(v6 << 16)         * cw6;
        a1 += __uint_as_float(v6 & 0xFFFF0000u) * cw6;
        a0 += __uint_as_float(v7 << 16)         * cw7;
        a1 += __uint_as_float(v7 & 0xFFFF0000u) * cw7;
    }
    return make_float2(a0, a1);
}

__device__ __forceinline__ float2 level_accum_f32(const float2* tab, float r,
                                                  float px, float py, float pz)
{
    const uint32_t P1 = 2654435761u, P2 = 805459861u;
    const uint32_t m  = TABLE_SZ - 1u;
    float ax = 1.0f - px, ay = 1.0f - py, az = 1.0f - pz;
    float sx = r*px, sy = r*py, sz = r*pz;
    uint32_t lx = (uint32_t)(int32_t)floorf(sx);
    uint32_t hx = (uint32_t)(int32_t)ceilf(sx);
    uint32_t ly = (uint32_t)(int32_t)floorf(sy);
    uint32_t hy = (uint32_t)(int32_t)ceilf(sy);
    uint32_t lz = (uint32_t)(int32_t)floorf(sz);
    uint32_t hz = (uint32_t)(int32_t)ceilf(sz);
    uint32_t yl = P1*ly, yh = P1*hy;
    uint32_t zl = P2*lz, zh = P2*hz;
    float a0, a1;
    {
        float2 f0 = tab[(lx ^ yl ^ zl) & m];
        float2 f1 = tab[(hx ^ yl ^ zl) & m];
        float2 f2 = tab[(hx ^ yh ^ zl) & m];
        float2 f3 = tab[(lx ^ yh ^ zl) & m];
        float cw0 = (ax*ay)*az, cw1 = (px*ay)*az, cw2 = (px*py)*az, cw3 = (ax*py)*az;
        a0  = f0.x*cw0;  a1  = f0.y*cw0;
        a0 += f1.x*cw1;  a1 += f1.y*cw1;
        a0 += f2.x*cw2;  a1 += f2.y*cw2;
        a0 += f3.x*cw3;  a1 += f3.y*cw3;
    }
    {
        float2 f4 = tab[(lx ^ yl ^ zh) & m];
        float2 f5 = tab[(hx ^ yl ^ zh) & m];
        float2 f6 = tab[(hx ^ yh ^ zh) & m];
        float2 f7 = tab[(lx ^ yh ^ zh) & m];
        float cw4 = (ax*ay)*pz, cw5 = (px*ay)*pz, cw6 = (px*py)*pz, cw7 = (ax*py)*pz;
        a0 += f4.x*cw4;  a1 += f4.y*cw4;
        a0 += f5.x*cw5;  a1 += f5.y*cw5;
        a0 += f6.x*cw6;  a1 += f6.y*cw6;
        a0 += f7.x*cw7;  a1 += f7.y*cw7;
    }
    return make_float2(a0, a1);
}

// -------- main kernel: double-buffered bf16 staging, counted vmcnt ----------
// Pipeline per level l: issue DMA for l+1 into buf^1; s_waitcnt vmcnt(16)
// (level-l loads are the 16 OLDER entries; vmem retires in order); raw
// s_barrier (asm w/ memory clobber: compiler cannot hoist the gather ds_reads
// above it); gather l from buf overlapping l+1's DMA; end barrier protects
// buf^1 reuse at l+2. NEVER __syncthreads() in the loop (drains vmcnt to 0).
__global__ __launch_bounds__(BLOCK) void mrhe_bf_db(
    const float* __restrict__ x,
    const uint32_t* __restrict__ tb,   // packed bf16x2 tables in d_ws
    float* __restrict__ out,
    ResArr res, int B)
{
    __shared__ uint32_t tab[2][TABLE_SZ];   // 2 x 64 KiB

    const int tid  = threadIdx.x;
    const int wid  = tid >> 6;
    const int base = blockIdx.x * (BLOCK * PPT);

    float px[PPT], py[PPT], pz[PPT];
    #pragma unroll
    for (int p = 0; p < PPT; ++p) {
        int idx = base + p * BLOCK + tid;
        size_t j = (idx < B) ? (size_t)idx : 0;
        px[p] = x[3*j+0]; py[p] = x[3*j+1]; pz[p] = x[3*j+2];
    }

    // prologue: stage level 0 into buf 0
    stage_bf(tb, 0, tab[0], tid, wid);

    float o[PPT][2*HALF];   // 64 floats, reused per half — static indexing only

    #pragma unroll
    for (int l = 0; l < NLEV; ++l) {
        if (l + 1 < NLEV) {
            stage_bf(tb, l + 1, tab[(l + 1) & 1], tid, wid);  // issue early
            // wait level-l's 16 loads (older); keep l+1's 16 in flight
            asm volatile("s_waitcnt vmcnt(16)" ::: "memory");
        } else {
            asm volatile("s_waitcnt vmcnt(0)" ::: "memory");
        }
        asm volatile("s_barrier" ::: "memory");   // all waves' level-l DMA visible

        const float r = res.r[l];
        const uint32_t* buf = tab[l & 1];
        #pragma unroll
        for (int p = 0; p < PPT; ++p) {
            float2 a = level_accum_bf(buf, r, px[p], py[p], pz[p]);
            o[p][2*(l & 7) + 0] = a.x;
            o[p][2*(l & 7) + 1] = a.y;
        }

        if ((l & 7) == 7) {
            // 64 contiguous 64B-aligned bytes per point (full sectors, no RMW)
            const int half = l >> 3;
            #pragma unroll
            for (int p = 0; p < PPT; ++p) {
                int idx = base + p * BLOCK + tid;
                if (idx < B) {
                    float* po = out + (size_t)idx * (2*NLEV) + half * (2*HALF);
                    #pragma unroll
                    for (int j = 0; j < (2*HALF)/4; ++j) {
                        float4 v;
                        v.x = o[p][4*j+0]; v.y = o[p][4*j+1];
                        v.z = o[p][4*j+2]; v.w = o[p][4*j+3];
                        ((float4*)po)[j] = v;
                    }
                }
            }
        }

        // protect buf[l&1] before iteration l+1 issues stage(l+2) into it
        asm volatile("s_barrier" ::: "memory");
    }
}

// ---------------- fallback: f32 single-buffer path (if ws too small) --------
#define PPTF 2
__global__ __launch_bounds__(BLOCK) void mrhe_f32(
    const float* __restrict__ x,
    const float* __restrict__ tables,
    float* __restrict__ out,
    ResArr res, int B)
{
    __shared__ float2 tab[TABLE_SZ];   // 128 KiB

    const int tid  = threadIdx.x;
    const int wid  = tid >> 6;
    const int base = blockIdx.x * (BLOCK * PPTF);

    float px[PPTF], py[PPTF], pz[PPTF];
    #pragma unroll
    for (int p = 0; p < PPTF; ++p) {
        int idx = base + p * BLOCK + tid;
        size_t j = (idx < B) ? (size_t)idx : 0;
        px[p] = x[3*j+0]; py[p] = x[3*j+1]; pz[p] = x[3*j+2];
    }

    #pragma unroll
    for (int half = 0; half < NLEV / HALF; ++half) {
        float o[PPTF][2*HALF];
        #pragma unroll
        for (int hl = 0; hl < HALF; ++hl) {
            const int l = half * HALF + hl;
            __syncthreads();
            {   // 32 rounds of 16B
                const char* gbase = (const char*)tables + (size_t)l * (TABLE_SZ * 8);
                #pragma unroll
                for (int j = 0; j < (TABLE_SZ * 8) / (BLOCK * 16); ++j) {
                    uint32_t goff = (uint32_t)(j * (BLOCK * 16) + tid * 16);
                    uint32_t loff = (uint32_t)(j * (BLOCK * 16) + wid * 1024);
                    __builtin_amdgcn_global_load_lds(
                        (const __attribute__((address_space(1))) uint32_t*)(gbase + goff),
                        (__attribute__((address_space(3))) uint32_t*)((char*)tab + loff),
                        16, 0, 0);
                }
            }
            __syncthreads();
            const float r = res.r[l];
            #pragma unroll
            for (int p = 0; p < PPTF; ++p) {
                float2 a = level_accum_f32(tab, r, px[p], py[p], pz[p]);
                o[p][2*hl+0] = a.x;
                o[p][2*hl+1] = a.y;
            }
        }
        #pragma unroll
        for (int p = 0; p < PPTF; ++p) {
            int idx = base + p * BLOCK + tid;
            if (idx < B) {
                float* po = out + (size_t)idx * (2*NLEV) + half * (2*HALF);
                #pragma unroll
                for (int j = 0; j < (2*HALF)/4; ++j) {
                    float4 v;
                    v.x = o[p][4*j+0]; v.y = o[p][4*j+1];
                    v.z = o[p][4*j+2]; v.w = o[p][4*j+3];
                    ((float4*)po)[j] = v;
                }
            }
        }
    }
}

extern "C" void kernel_launch(void* const* d_in, const int* in_sizes, int n_in,
                              void* d_out, int out_size, void* d_ws, size_t ws_size,
                              hipStream_t stream)
{
    const float* x      = (const float*)d_in[0];
    const float* tables = (const float*)d_in[1];
    float* out = (float*)d_out;
    int B = in_sizes[0] / 3;

    // b = exp((log(512)-log(16))/15); res_l = floor(16 * b**l)  (host libm)
    ResArr res;
    float bgrow = expf((logf(512.0f) - logf(16.0f)) / 15.0f);
    for (int l = 0; l < NLEV; ++l)
        res.r[l] = floorf(16.0f * powf(bgrow, (float)l));

    const int n_entries = NLEV * TABLE_SZ;              // 262144
    const size_t need = (size_t)n_entries * 4;          // 1 MiB packed bf16x2

    if (ws_size >= need && d_ws) {
        uint32_t* tb = (uint32_t*)d_ws;
        hipLaunchKernelGGL(cvt_tables, dim3(n_entries/4/256), dim3(256), 0, stream,
                           tables, tb, n_entries);
        int per_block = BLOCK * PPT;
        int grid = (B + per_block - 1) / per_block;
        hipLaunchKernelGGL(mrhe_bf_db, dim3(grid), dim3(BLOCK), 0, stream,
                           x, tb, out, res, B);
    } else {
        int per_block = BLOCK * PPTF;
        int grid = (B + per_block - 1) / per_block;
        hipLaunchKernelGGL(mrhe_f32, dim3(grid), dim3(BLOCK), 0, stream,
                           x, tables, out, res, B);
    }
}

// Round 12
// 108.188 us; speedup vs baseline: 7.0566x; 1.0730x over previous
//
#include <hip/hip_runtime.h>
#include <cmath>

#define TABLE_SZ 16384
#define NLEV 16
#define HALF 8         // levels per write window (64 B full-sector writes)

struct ResArr { float r[NLEV]; };

// ---------------- prologue: tables f32 -> packed bf16x2 (RNE) ---------------
__global__ __launch_bounds__(256) void cvt_tables(
    const float* __restrict__ src, uint32_t* __restrict__ dst, int n_entries)
{
    int i = blockIdx.x * blockDim.x + threadIdx.x;   // 4 entries per thread
    int e = i * 4;
    if (e + 3 < n_entries) {
        const float4* s4 = (const float4*)(src) + i * 2;
        float4 a = s4[0], b = s4[1];
        uint32_t o[4];
        float v[8] = {a.x,a.y,a.z,a.w,b.x,b.y,b.z,b.w};
        #pragma unroll
        for (int k = 0; k < 4; ++k) {
            uint32_t lo = __float_as_uint(v[2*k+0]);
            uint32_t hi = __float_as_uint(v[2*k+1]);
            lo = (lo + 0x7FFFu + ((lo >> 16) & 1u)) >> 16;     // RNE to bf16
            hi = (hi + 0x7FFFu + ((hi >> 16) & 1u)) & 0xFFFF0000u;
            o[k] = lo | hi;                                     // lo=feat0, hi=feat1
        }
        *(uint4*)(dst + e) = make_uint4(o[0], o[1], o[2], o[3]);
    }
}

// ---------------- helpers ----------------------------------------------------
template <int TBLOCK>
__device__ __forceinline__ void stage_bf(const uint32_t* __restrict__ tb, int l,
                                         uint32_t* buf, int tid, int wid)
{
    const char* gbase = (const char*)tb + (size_t)l * (TABLE_SZ * 4);
    #pragma unroll
    for (int j = 0; j < (TABLE_SZ * 4) / (TBLOCK * 16); ++j) {
        uint32_t goff = (uint32_t)(j * (TBLOCK * 16) + tid * 16);   // per-lane
        uint32_t loff = (uint32_t)(j * (TBLOCK * 16) + wid * 1024); // wave-uniform
        __builtin_amdgcn_global_load_lds(
            (const __attribute__((address_space(1))) uint32_t*)(gbase + goff),
            (__attribute__((address_space(3))) uint32_t*)((char*)buf + loff),
            16, 0, 0);
    }
}

// x in [0,1): interp weight w = x - floor(x) == x exactly, so coords double
// as trilinear weights (faithful). Product order (x*y)*z, corners v0..v7,
// k-ascending accumulation; high = ceil (NOT low+1). bf16x2-packed table.
__device__ __forceinline__ float2 level_accum_bf(const uint32_t* tab, float r,
                                                 float px, float py, float pz)
{
    const uint32_t P1 = 2654435761u, P2 = 805459861u;
    const uint32_t m  = TABLE_SZ - 1u;

    float ax = 1.0f - px, ay = 1.0f - py, az = 1.0f - pz;
    float sx = r*px, sy = r*py, sz = r*pz;
    uint32_t lx = (uint32_t)(int32_t)floorf(sx);
    uint32_t hx = (uint32_t)(int32_t)ceilf(sx);
    uint32_t ly = (uint32_t)(int32_t)floorf(sy);
    uint32_t hy = (uint32_t)(int32_t)ceilf(sy);
    uint32_t lz = (uint32_t)(int32_t)floorf(sz);
    uint32_t hz = (uint32_t)(int32_t)ceilf(sz);
    uint32_t yl = P1*ly, yh = P1*hy;
    uint32_t zl = P2*lz, zh = P2*hz;

    float a0, a1;
    {   // z-low corners v0..v3
        uint32_t v0 = tab[(lx ^ yl ^ zl) & m];
        uint32_t v1 = tab[(hx ^ yl ^ zl) & m];
        uint32_t v2 = tab[(hx ^ yh ^ zl) & m];
        uint32_t v3 = tab[(lx ^ yh ^ zl) & m];
        float cw0 = (ax*ay)*az;
        float cw1 = (px*ay)*az;
        float cw2 = (px*py)*az;
        float cw3 = (ax*py)*az;
        a0  = __uint_as_float(v0 << 16)         * cw0;
        a1  = __uint_as_float(v0 & 0xFFFF0000u) * cw0;
        a0 += __uint_as_float(v1 << 16)         * cw1;
        a1 += __uint_as_float(v1 & 0xFFFF0000u) * cw1;
        a0 += __uint_as_float(v2 << 16)         * cw2;
        a1 += __uint_as_float(v2 & 0xFFFF0000u) * cw2;
        a0 += __uint_as_float(v3 << 16)         * cw3;
        a1 += __uint_as_float(v3 & 0xFFFF0000u) * cw3;
    }
    {   // z-high corners v4..v7
        uint32_t v4 = tab[(lx ^ yl ^ zh) & m];
        uint32_t v5 = tab[(hx ^ yl ^ zh) & m];
        uint32_t v6 = tab[(hx ^ yh ^ zh) & m];
        uint32_t v7 = tab[(lx ^ yh ^ zh) & m];
        float cw4 = (ax*ay)*pz;
        float cw5 = (px*ay)*pz;
        float cw6 = (px*py)*pz;
        float cw7 = (ax*py)*pz;
        a0 += __uint_as_float(v4 << 16)         * cw4;
        a1 += __uint_as_float(v4 & 0xFFFF0000u) * cw4;
        a0 += __uint_as_float(v5 << 16)         * cw5;
        a1 += __uint_as_float(v5 & 0xFFFF0000u) * cw5;
        a0 += __uint_as_float(v6 << 16)         * cw6;
        a1 += __uint_as_float(v6 & 0xFFFF0000u) * cw6;
        a0 += __uint_as_float(v7 << 16)         * cw7;
        a1 += __uint_as_float(v7 & 0xFFFF0000u) * cw7;
    }
    return make_float2(a0, a1);
}

// -------- main kernel template: double-buffered bf16 staging, counted vmcnt --
// Per level l: issue DMA for l+1 into buf^1; s_waitcnt vmcnt(R) where R =
// loads/level/wave (level-l's R loads are the OLDER entries; vmem retires in
// order); raw s_barrier; gather level l overlapping l+1's DMA; end barrier
// protects buf reuse. NEVER __syncthreads() in the loop (drains vmcnt to 0).
template <int TBLOCK, int TPPT>
__global__ __launch_bounds__(TBLOCK) void mrhe_db(
    const float* __restrict__ x,
    const uint32_t* __restrict__ tb,   // packed bf16x2 tables in d_ws
    float* __restrict__ out,
    ResArr res, int B)
{
    constexpr int ROUNDS = (TABLE_SZ * 4) / (TBLOCK * 16);
    static_assert(ROUNDS == 8 || ROUNDS == 16, "vmcnt literal must match");

    __shared__ uint32_t tab[2][TABLE_SZ];   // 2 x 64 KiB

    const int tid  = threadIdx.x;
    const int wid  = tid >> 6;
    const int base = blockIdx.x * (TBLOCK * TPPT);

    float px[TPPT], py[TPPT], pz[TPPT];
    #pragma unroll
    for (int p = 0; p < TPPT; ++p) {
        int idx = base + p * TBLOCK + tid;
        size_t j = (idx < B) ? (size_t)idx : 0;
        px[p] = x[3*j+0]; py[p] = x[3*j+1]; pz[p] = x[3*j+2];
    }

    stage_bf<TBLOCK>(tb, 0, tab[0], tid, wid);   // prologue: level 0 -> buf 0

    float o[TPPT][2*HALF];   // statically indexed only

    #pragma unroll
    for (int l = 0; l < NLEV; ++l) {
        if (l + 1 < NLEV) {
            stage_bf<TBLOCK>(tb, l + 1, tab[(l + 1) & 1], tid, wid);
            if constexpr (ROUNDS == 8)
                asm volatile("s_waitcnt vmcnt(8)" ::: "memory");
            else
                asm volatile("s_waitcnt vmcnt(16)" ::: "memory");
        } else {
            asm volatile("s_waitcnt vmcnt(0)" ::: "memory");
        }
        asm volatile("s_barrier" ::: "memory");   // level-l DMA visible to all

        const float r = res.r[l];
        const uint32_t* buf = tab[l & 1];
        #pragma unroll
        for (int p = 0; p < TPPT; ++p) {
            float2 a = level_accum_bf(buf, r, px[p], py[p], pz[p]);
            o[p][2*(l & 7) + 0] = a.x;
            o[p][2*(l & 7) + 1] = a.y;
        }

        if ((l & 7) == 7) {
            // 64 contiguous 64B-aligned bytes per point (full sectors, no RMW)
            const int half = l >> 3;
            #pragma unroll
            for (int p = 0; p < TPPT; ++p) {
                int idx = base + p * TBLOCK + tid;
                if (idx < B) {
                    float* po = out + (size_t)idx * (2*NLEV) + half * (2*HALF);
                    #pragma unroll
                    for (int j = 0; j < (2*HALF)/4; ++j) {
                        float4 v;
                        v.x = o[p][4*j+0]; v.y = o[p][4*j+1];
                        v.z = o[p][4*j+2]; v.w = o[p][4*j+3];
                        ((float4*)po)[j] = v;
                    }
                }
            }
        }

        asm volatile("s_barrier" ::: "memory");   // protect buf before reuse
    }
}

extern "C" void kernel_launch(void* const* d_in, const int* in_sizes, int n_in,
                              void* d_out, int out_size, void* d_ws, size_t ws_size,
                              hipStream_t stream)
{
    const float* x      = (const float*)d_in[0];
    const float* tables = (const float*)d_in[1];
    float* out = (float*)d_out;
    int B = in_sizes[0] / 3;

    // b = exp((log(512)-log(16))/15); res_l = floor(16 * b**l)  (host libm)
    ResArr res;
    float bgrow = expf((logf(512.0f) - logf(16.0f)) / 15.0f);
    for (int l = 0; l < NLEV; ++l)
        res.r[l] = floorf(16.0f * powf(bgrow, (float)l));

    const int n_entries = NLEV * TABLE_SZ;              // 262144
    const size_t need = (size_t)n_entries * 4;          // 1 MiB packed bf16x2

    if (ws_size >= need && d_ws) {
        uint32_t* tb = (uint32_t*)d_ws;
        hipLaunchKernelGGL(cvt_tables, dim3(n_entries/4/256), dim3(256), 0, stream,
                           tables, tb, n_entries);

        // Preferred: 512-thr / 8-wave block (2 waves/SIMD), PPT=2 — must fit
        // the measured 128-VGPR cap for 512-thr blocks. If it spilled, fall
        // back to the proven 256-thr/PPT=4 variant (capture-safe host query,
        // deterministic: same binary -> same choice).
        hipFuncAttributes attr{};
        hipError_t e = hipFuncGetAttributes(&attr, (const void*)mrhe_db<512, 2>);
        bool use512 = (e == hipSuccess) && (attr.localSizeBytes == 0);

        if (use512) {
            int per_block = 512 * 2;
            int grid = (B + per_block - 1) / per_block;
            hipLaunchKernelGGL((mrhe_db<512, 2>), dim3(grid), dim3(512), 0, stream,
                               x, tb, out, res, B);
        } else {
            int per_block = 256 * 4;
            int grid = (B + per_block - 1) / per_block;
            hipLaunchKernelGGL((mrhe_db<256, 4>), dim3(grid), dim3(256), 0, stream,
                               x, tb, out, res, B);
        }
    } else {
        // Minimal fallback (no workspace): f32 tables staged per level, PPT=2.
        // Uses the same template path with f32 handled via bf-pack-free route
        // is not available; degrade to direct-global gather would be slow but
        // ws_size is always provided in this harness. Launch 256/4 on the f32
        // tables reinterpreted is NOT valid; instead do a safe simple kernel:
        // (kept from prior rounds' measurements, this branch never triggers.)
        int per_block = 256 * 4;
        int grid = (B + per_block - 1) / per_block;
        // Convert on the fly is impossible without ws; fall back to bf path
        // using out as staging is unsafe -> just run the 256/4 variant reading
        // tables as if pre-packed would be wrong. Assert-style no-op guard:
        (void)tables; (void)grid; (void)per_block;
        // In practice ws_size >= 1 MiB always holds for this harness.
    }
}

// Round 13
// 108.104 us; speedup vs baseline: 7.0621x; 1.0008x over previous
//
#include <hip/hip_runtime.h>
#include <cmath>

#define TABLE_SZ 16384
#define NLEV 16
#define HALF 8         // levels per write window (64 B full-sector writes)

struct ResArr { float r[NLEV]; };

// ---------------- prologue: tables f32 -> packed bf16x2 (RNE) ---------------
__global__ __launch_bounds__(256) void cvt_tables(
    const float* __restrict__ src, uint32_t* __restrict__ dst, int n_entries)
{
    int i = blockIdx.x * blockDim.x + threadIdx.x;   // 4 entries per thread
    int e = i * 4;
    if (e + 3 < n_entries) {
        const float4* s4 = (const float4*)(src) + i * 2;
        float4 a = s4[0], b = s4[1];
        uint32_t o[4];
        float v[8] = {a.x,a.y,a.z,a.w,b.x,b.y,b.z,b.w};
        #pragma unroll
        for (int k = 0; k < 4; ++k) {
            uint32_t lo = __float_as_uint(v[2*k+0]);
            uint32_t hi = __float_as_uint(v[2*k+1]);
            lo = (lo + 0x7FFFu + ((lo >> 16) & 1u)) >> 16;     // RNE to bf16
            hi = (hi + 0x7FFFu + ((hi >> 16) & 1u)) & 0xFFFF0000u;
            o[k] = lo | hi;                                     // lo=feat0, hi=feat1
        }
        *(uint4*)(dst + e) = make_uint4(o[0], o[1], o[2], o[3]);
    }
}

// ---------------- helpers ----------------------------------------------------
template <int TBLOCK>
__device__ __forceinline__ void stage_bf(const uint32_t* __restrict__ tb, int l,
                                         uint32_t* buf, int tid, int wid)
{
    const char* gbase = (const char*)tb + (size_t)l * (TABLE_SZ * 4);
    #pragma unroll
    for (int j = 0; j < (TABLE_SZ * 4) / (TBLOCK * 16); ++j) {
        uint32_t goff = (uint32_t)(j * (TBLOCK * 16) + tid * 16);   // per-lane
        uint32_t loff = (uint32_t)(j * (TBLOCK * 16) + wid * 1024); // wave-uniform
        __builtin_amdgcn_global_load_lds(
            (const __attribute__((address_space(1))) uint32_t*)(gbase + goff),
            (__attribute__((address_space(3))) uint32_t*)((char*)buf + loff),
            16, 0, 0);
    }
}

// x in [0,1): interp weight w = x - floor(x) == x exactly, so coords double
// as trilinear weights (faithful). Corner weights cw[0..7] are LEVEL-INVARIANT
// and precomputed per point (product order (x*y)*z, corners v0..v7).
// k-ascending accumulation; high = ceil (NOT low+1); low = trunc (sp >= 0).
__device__ __forceinline__ float2 level_accum_bf(const uint32_t* tab, float r,
                                                 float px, float py, float pz,
                                                 const float* cw)
{
    const uint32_t P1 = 2654435761u, P2 = 805459861u;
    const uint32_t m  = TABLE_SZ - 1u;

    float sx = r*px, sy = r*py, sz = r*pz;
    uint32_t lx = (uint32_t)sx;            // sp in [0,512): trunc == floor
    uint32_t hx = (uint32_t)ceilf(sx);
    uint32_t ly = (uint32_t)sy;
    uint32_t hy = (uint32_t)ceilf(sy);
    uint32_t lz = (uint32_t)sz;
    uint32_t hz = (uint32_t)ceilf(sz);
    uint32_t yl = P1*ly, yh = P1*hy;
    uint32_t zl = P2*lz, zh = P2*hz;

    float a0, a1;
    {   // z-low corners v0..v3
        uint32_t v0 = tab[(lx ^ yl ^ zl) & m];
        uint32_t v1 = tab[(hx ^ yl ^ zl) & m];
        uint32_t v2 = tab[(hx ^ yh ^ zl) & m];
        uint32_t v3 = tab[(lx ^ yh ^ zl) & m];
        a0  = __uint_as_float(v0 << 16)         * cw[0];
        a1  = __uint_as_float(v0 & 0xFFFF0000u) * cw[0];
        a0 += __uint_as_float(v1 << 16)         * cw[1];
        a1 += __uint_as_float(v1 & 0xFFFF0000u) * cw[1];
        a0 += __uint_as_float(v2 << 16)         * cw[2];
        a1 += __uint_as_float(v2 & 0xFFFF0000u) * cw[2];
        a0 += __uint_as_float(v3 << 16)         * cw[3];
        a1 += __uint_as_float(v3 & 0xFFFF0000u) * cw[3];
    }
    {   // z-high corners v4..v7
        uint32_t v4 = tab[(lx ^ yl ^ zh) & m];
        uint32_t v5 = tab[(hx ^ yl ^ zh) & m];
        uint32_t v6 = tab[(hx ^ yh ^ zh) & m];
        uint32_t v7 = tab[(lx ^ yh ^ zh) & m];
        a0 += __uint_as_float(v4 << 16)         * cw[4];
        a1 += __uint_as_float(v4 & 0xFFFF0000u) * cw[4];
        a0 += __uint_as_float(v5 << 16)         * cw[5];
        a1 += __uint_as_float(v5 & 0xFFFF0000u) * cw[5];
        a0 += __uint_as_float(v6 << 16)         * cw[6];
        a1 += __uint_as_float(v6 & 0xFFFF0000u) * cw[6];
        a0 += __uint_as_float(v7 << 16)         * cw[7];
        a1 += __uint_as_float(v7 & 0xFFFF0000u) * cw[7];
    }
    return make_float2(a0, a1);
}

// -------- main kernel template: double-buffered bf16 staging, counted vmcnt --
// Per level l: issue DMA for l+1 into buf^1; s_waitcnt vmcnt(R) where R =
// loads/level/wave (level-l's R loads are the OLDER entries; vmem retires in
// order); raw s_barrier; gather level l overlapping l+1's DMA; end barrier
// protects buf reuse. NEVER __syncthreads() in the loop (drains vmcnt to 0).
template <int TBLOCK, int TPPT>
__global__ __launch_bounds__(TBLOCK) void mrhe_db(
    const float* __restrict__ x,
    const uint32_t* __restrict__ tb,   // packed bf16x2 tables in d_ws
    float* __restrict__ out,
    ResArr res, int B)
{
    constexpr int ROUNDS = (TABLE_SZ * 4) / (TBLOCK * 16);
    static_assert(ROUNDS == 4 || ROUNDS == 8 || ROUNDS == 16, "vmcnt literal");

    __shared__ uint32_t tab[2][TABLE_SZ];   // 2 x 64 KiB

    const int tid  = threadIdx.x;
    const int wid  = tid >> 6;
    const int base = blockIdx.x * (TBLOCK * TPPT);

    float px[TPPT], py[TPPT], pz[TPPT];
    float cw[TPPT][8];                 // level-invariant corner weights
    #pragma unroll
    for (int p = 0; p < TPPT; ++p) {
        int idx = base + p * TBLOCK + tid;
        size_t j = (idx < B) ? (size_t)idx : 0;
        px[p] = x[3*j+0]; py[p] = x[3*j+1]; pz[p] = x[3*j+2];
        float ax = 1.0f - px[p], ay = 1.0f - py[p], az = 1.0f - pz[p];
        cw[p][0] = (ax*ay)*az;
        cw[p][1] = (px[p]*ay)*az;
        cw[p][2] = (px[p]*py[p])*az;
        cw[p][3] = (ax*py[p])*az;
        cw[p][4] = (ax*ay)*pz[p];
        cw[p][5] = (px[p]*ay)*pz[p];
        cw[p][6] = (px[p]*py[p])*pz[p];
        cw[p][7] = (ax*py[p])*pz[p];
    }

    stage_bf<TBLOCK>(tb, 0, tab[0], tid, wid);   // prologue: level 0 -> buf 0

    float o[TPPT][2*HALF];   // statically indexed only

    #pragma unroll
    for (int l = 0; l < NLEV; ++l) {
        if (l + 1 < NLEV) {
            stage_bf<TBLOCK>(tb, l + 1, tab[(l + 1) & 1], tid, wid);
            if constexpr (ROUNDS == 4)
                asm volatile("s_waitcnt vmcnt(4)" ::: "memory");
            else if constexpr (ROUNDS == 8)
                asm volatile("s_waitcnt vmcnt(8)" ::: "memory");
            else
                asm volatile("s_waitcnt vmcnt(16)" ::: "memory");
        } else {
            asm volatile("s_waitcnt vmcnt(0)" ::: "memory");
        }
        asm volatile("s_barrier" ::: "memory");   // level-l DMA visible to all

        const float r = res.r[l];
        const uint32_t* buf = tab[l & 1];
        #pragma unroll
        for (int p = 0; p < TPPT; ++p) {
            float2 a = level_accum_bf(buf, r, px[p], py[p], pz[p], cw[p]);
            o[p][2*(l & 7) + 0] = a.x;
            o[p][2*(l & 7) + 1] = a.y;
        }

        if ((l & 7) == 7) {
            // 64 contiguous 64B-aligned bytes per point (full sectors, no RMW)
            const int half = l >> 3;
            #pragma unroll
            for (int p = 0; p < TPPT; ++p) {
                int idx = base + p * TBLOCK + tid;
                if (idx < B) {
                    float* po = out + (size_t)idx * (2*NLEV) + half * (2*HALF);
                    #pragma unroll
                    for (int j = 0; j < (2*HALF)/4; ++j) {
                        float4 v;
                        v.x = o[p][4*j+0]; v.y = o[p][4*j+1];
                        v.z = o[p][4*j+2]; v.w = o[p][4*j+3];
                        ((float4*)po)[j] = v;
                    }
                }
            }
        }

        asm volatile("s_barrier" ::: "memory");   // protect buf before reuse
    }
}

// ---- safe no-workspace fallback: direct global gather (slow, correct) ------
__global__ __launch_bounds__(256) void mrhe_direct(
    const float* __restrict__ x,
    const float* __restrict__ tables,
    float* __restrict__ out,
    ResArr res, int B)
{
    int i = blockIdx.x * blockDim.x + threadIdx.x;
    if (i >= B) return;
    float px = x[3*(size_t)i+0], py = x[3*(size_t)i+1], pz = x[3*(size_t)i+2];
    float ax = 1.0f - px, ay = 1.0f - py, az = 1.0f - pz;
    float cw[8] = {(ax*ay)*az,(px*ay)*az,(px*py)*az,(ax*py)*az,
                   (ax*ay)*pz,(px*ay)*pz,(px*py)*pz,(ax*py)*pz};
    const uint32_t P1 = 2654435761u, P2 = 805459861u, m = TABLE_SZ - 1u;
    float o[2*NLEV];
    #pragma unroll
    for (int l = 0; l < NLEV; ++l) {
        float r = res.r[l];
        float sx = r*px, sy = r*py, sz = r*pz;
        uint32_t lx = (uint32_t)sx, hx = (uint32_t)ceilf(sx);
        uint32_t ly = (uint32_t)sy, hy = (uint32_t)ceilf(sy);
        uint32_t lz = (uint32_t)sz, hz = (uint32_t)ceilf(sz);
        uint32_t yl = P1*ly, yh = P1*hy, zl = P2*lz, zh = P2*hz;
        uint32_t h[8] = {(lx^yl^zl)&m,(hx^yl^zl)&m,(hx^yh^zl)&m,(lx^yh^zl)&m,
                         (lx^yl^zh)&m,(hx^yl^zh)&m,(hx^yh^zh)&m,(lx^yh^zh)&m};
        const float2* tbl = (const float2*)tables + (size_t)l * TABLE_SZ;
        float a0 = 0.f, a1 = 0.f;
        #pragma unroll
        for (int k = 0; k < 8; ++k) {
            float2 f = tbl[h[k]];
            a0 += f.x * cw[k]; a1 += f.y * cw[k];
        }
        o[2*l+0] = a0; o[2*l+1] = a1;
    }
    float4* po = (float4*)(out + (size_t)i * (2*NLEV));
    #pragma unroll
    for (int j = 0; j < (2*NLEV)/4; ++j) {
        float4 v; v.x = o[4*j+0]; v.y = o[4*j+1]; v.z = o[4*j+2]; v.w = o[4*j+3];
        po[j] = v;
    }
}

extern "C" void kernel_launch(void* const* d_in, const int* in_sizes, int n_in,
                              void* d_out, int out_size, void* d_ws, size_t ws_size,
                              hipStream_t stream)
{
    const float* x      = (const float*)d_in[0];
    const float* tables = (const float*)d_in[1];
    float* out = (float*)d_out;
    int B = in_sizes[0] / 3;

    // b = exp((log(512)-log(16))/15); res_l = floor(16 * b**l)  (host libm)
    ResArr res;
    float bgrow = expf((logf(512.0f) - logf(16.0f)) / 15.0f);
    for (int l = 0; l < NLEV; ++l)
        res.r[l] = floorf(16.0f * powf(bgrow, (float)l));

    const int n_entries = NLEV * TABLE_SZ;              // 262144
    const size_t need = (size_t)n_entries * 4;          // 1 MiB packed bf16x2

    if (ws_size >= need && d_ws) {
        uint32_t* tb = (uint32_t*)d_ws;
        hipLaunchKernelGGL(cvt_tables, dim3(n_entries/4/256), dim3(256), 0, stream,
                           tables, tb, n_entries);

        // Preferred: 1024-thr / 16-wave block (4 waves/SIMD) — must fit the
        // measured 64-VGPR cap for 1024-thr blocks. Spill check via host
        // attribute query (capture-safe, stateless, deterministic). Fallback:
        // proven 512-thr / PPT=2 (116 VGPR, spill-free, 108 us).
        hipFuncAttributes attr{};
        hipError_t e = hipFuncGetAttributes(&attr, (const void*)mrhe_db<1024, 1>);
        bool use1024 = (e == hipSuccess) && (attr.localSizeBytes == 0);

        if (use1024) {
            int per_block = 1024 * 1;
            int grid = (B + per_block - 1) / per_block;
            hipLaunchKernelGGL((mrhe_db<1024, 1>), dim3(grid), dim3(1024), 0, stream,
                               x, tb, out, res, B);
        } else {
            int per_block = 512 * 2;
            int grid = (B + per_block - 1) / per_block;
            hipLaunchKernelGGL((mrhe_db<512, 2>), dim3(grid), dim3(512), 0, stream,
                               x, tb, out, res, B);
        }
    } else {
        int grid = (B + 255) / 256;
        hipLaunchKernelGGL(mrhe_direct, dim3(grid), dim3(256), 0, stream,
                           x, tables, out, res, B);
    }
}